// Round 5
// baseline (525.666 us; speedup 1.0000x reference)
//
#include <hip/hip_runtime.h>
#include <hip/hip_bf16.h>
#include <math.h>

#define NB 4096
#define NN 64
#define NM 4
#define NF 128
#define NOBS 64
#define ND 64
#define NH 4
#define NLAYER 2
#define NFF 128
#define NHID 64
#define NOUT 8
#define EPSC 1e-6f

typedef unsigned short ushort_t;
typedef __attribute__((ext_vector_type(8))) short short8v;   // 8 bf16 (4 VGPR) MFMA A/B frag
typedef __attribute__((ext_vector_type(4))) float f32x4;     // MFMA C/D frag

#define MFMA16(a, b, c) __builtin_amdgcn_mfma_f32_16x16x32_bf16((a), (b), (c), 0, 0, 0)

struct GParams {
    const float* x_anc; const float* g_anc; const float* x_nei; const float* ew_anc;
    const float* W_anc; const float* b_anc;
    const float* Wv_emb; const float* bv_emb; const float* Wv_val; const float* bv_val;
    const float* r_Win; const float* r_bin; const float* r_lng; const float* r_lnb;
    const float* r_W1; const float* r_b1; const float* r_W2; const float* r_b2;
    const float* r_Wview; const float* r_bview; const float* r_Wmode; const float* r_bmode;
    const float* log_tau;
    const float* L_Wq; const float* L_Wk; const float* L_Wv; const float* L_Wo;
    const float* L_ln1g; const float* L_ln1b; const float* L_ln2g; const float* L_ln2b;
    const float* L_Wf1; const float* L_bf1; const float* L_Wf2; const float* L_bf2;
    const float* p_lng; const float* p_lnb; const float* p_W1; const float* p_b1;
    const float* p_W2; const float* p_b2;
    const uint4* wsf;     // prepped split-bf16 weight fragments (see prep_w)
    float* out;
};

__device__ __forceinline__ float gelu_f(float x) {
    return 0.5f * x * (1.0f + erff(x * 0.7071067811865476f));
}
__device__ __forceinline__ float wsum64(float v) {
#pragma unroll
    for (int off = 32; off > 0; off >>= 1) v += __shfl_xor(v, off, 64);
    return v;
}
__device__ __forceinline__ float wmax64(float v) {
#pragma unroll
    for (int off = 32; off > 0; off >>= 1) v = fmaxf(v, __shfl_xor(v, off, 64));
    return v;
}
__device__ __forceinline__ float bf2f(ushort_t u) {
    union { unsigned int i; float f; } c; c.i = ((unsigned int)u) << 16; return c.f;
}
__device__ __forceinline__ ushort_t f2bf(float f) {
    __hip_bfloat16 h = __float2bfloat16(f);
    ushort_t u; __builtin_memcpy(&u, &h, 2); return u;
}
__device__ __forceinline__ short8v ld_frag(const uint4* p) {
    union { uint4 q; short8v v; } u; u.q = *p; return u.v;
}

// ---------------------------------------------------------------------------
// Weight prep (unchanged from round 4): split-bf16 MFMA B-fragments in d_ws.
// ---------------------------------------------------------------------------
__global__ void prep_w(const float* Wv_emb, const float* L_Wk, const float* L_Wv, uint4* ws)
{
    int task = blockIdx.x * 256 + threadIdx.x;    // 48 frags * 64 lanes = 3072
    if (task >= 3072) return;
    int lane = task & 63;
    int frag = task >> 6;                         // 0..47
    const float* src; int ks, ct; uint4 *dhi, *dlo;
    if (frag < 16) {                              // W0
        ks = frag >> 2; ct = frag & 3;
        src = Wv_emb;
        dhi = ws + (size_t)frag * 64 + lane;
        dlo = ws + 1024 + (size_t)frag * 64 + lane;
    } else {
        int g = frag - 16;                        // 0..31
        int matidx = g >> 3;                      // 0=K0 1=V0 2=K1 3=V1
        int fi = g & 7;
        ks = fi >> 2; ct = fi & 3;                // ks in {0,1}
        src = ((matidx & 1) ? L_Wv : L_Wk) + (size_t)(matidx >> 1) * (ND * ND);
        dhi = ws + 2048 + (size_t)matidx * 1024 + (size_t)fi * 64 + lane;
        dlo = dhi + 512;
    }
    union { ushort_t u[8]; uint4 q; } hi, lo;
#pragma unroll
    for (int i = 0; i < 8; i++) {
        int k = ks * 32 + (lane >> 4) * 8 + i;
        int d = ct * 16 + (lane & 15);
        float w = src[k * ND + d];
        ushort_t h = f2bf(w);
        hi.u[i] = h;
        lo.u[i] = f2bf(w - bf2f(h));
    }
    *dhi = hi.q;
    *dlo = lo.q;
}

// launch_bounds notes (measured): (256,4) clamps to 64 VGPR -> spills (662us);
// (256,2) only 2 blocks resident; (256,3) = 3 blocks/CU, no spill -> best.
__global__ __launch_bounds__(256, 3)
void gora_fused(GParams P)
{
    const int b = blockIdx.x;
    const int t = threadIdx.x;
    const int lane = t & 63;
    const int wave = t >> 6;

    // ---- LDS ~46.3 KB -> 3 blocks/CU ----
    __shared__ alignas(16) char u1buf[NN * NF * 2];  // 16 KB: xsf bf16 then hns f32 (swizzled)
    __shared__ float hv[NM][ND];
    __shared__ __hip_bfloat16 kb16[NN][ND + 2];      // 8.25KB K (padded rows: 66 elems)
    __shared__ __hip_bfloat16 vb16[NN][ND + 2];      // 8.25KB V
    __shared__ float ew_s[NN * NM];                  // raw masked ew  [n*4+m]
    __shared__ float winv[NM], wssum[NM];
    __shared__ float xa[NF];
    __shared__ float ga[NOBS];
    __shared__ float xw[NM][NF];
    __shared__ float pvc[NM][ND];
    __shared__ float hfin[NHID];
    __shared__ float pi_raw[NH * NM];
    __shared__ float pi_s[NH][NM];
    __shared__ float beta_s[NH];
    __shared__ float gate_s[NH][NN];
    __shared__ float xcur[ND];
    __shared__ float qv[ND];
    __shared__ float attn_s[NH][NN];
    __shared__ float ffs[NFF];
    __shared__ float sA[ND];
    __shared__ float sB[ND];
    // wave-split-K partial buffers (phase-reused):
    __shared__ float part_a[4][ND];   // h_anc partials, then r-MLP partials
    __shared__ float part_b[4][ND];   // PV partials, FF2 partials, tail p_W1 partials
    __shared__ float part_c[4][ND];   // Wo partials

    // ================= loads =================
    {
        float e = P.ew_anc[(size_t)b * NN * NM + t];   // 256 = N*M exactly
        ew_s[t] = (e > 0.0f) ? e : 0.0f;               // ew * (ew>0)
    }
    if (t < NF) xa[t] = P.x_anc[(size_t)b * NF + t];
    else if (t < NF + NOBS) ga[t - NF] = P.g_anc[(size_t)b * NOBS + (t - NF)];
    {
        // xsf swizzled store: elem (n,f) byte = n*256 + ((f>>3 ^ (n&15))<<4) + (f&7)*2
        const float4* xn4 = (const float4*)(P.x_nei + (size_t)b * NN * NF);
#pragma unroll
        for (int i = 0; i < 8; i++) {
            int i4 = t + i * 256;                      // 2048 float4 total
            float4 v4 = xn4[i4];
            __hip_bfloat162 p0, p1;
            p0.x = __float2bfloat16(v4.x); p0.y = __float2bfloat16(v4.y);
            p1.x = __float2bfloat16(v4.z); p1.y = __float2bfloat16(v4.w);
            int n = i4 >> 5;
            int c = (i4 >> 1) & 15;
            char* dstb = u1buf + n * 256 + ((c ^ (n & 15)) << 4) + (i4 & 1) * 8;
            ((__hip_bfloat162*)dstb)[0] = p0;
            ((__hip_bfloat162*)dstb)[1] = p1;
        }
    }
    __syncthreads();

    // ======== view-weight norms (t<4) + h_anc wave-split (all threads) ========
    if (t < NM) {
        float s = 0.0f;
        for (int n = 0; n < NN; n++) s += ew_s[n * NM + t];
        float c = fmaxf(s, EPSC);
        winv[t]  = 1.0f / c;
        wssum[t] = s / c;
    }
    {
        // h_anc = x_anc @ W_anc + b_anc: wave w sums k in [32w, 32w+32)
        const float* Wr = P.W_anc + (wave * 32) * ND + lane;
        float a0 = 0.f, a1 = 0.f;
#pragma unroll
        for (int f = 0; f < 32; f += 2) {
            a0 += xa[wave * 32 + f] * Wr[f * ND];
            a1 += xa[wave * 32 + f + 1] * Wr[(f + 1) * ND];
        }
        part_a[wave][lane] = a0 + a1;   // reduced (+ bias) in ctx_vec phase
    }
    __syncthreads();

    // ======== xw[m][f] = sum_n w[m,n] * x_nei[n,f]  (swizzled xsf reads) ========
    {
        int f = t & (NF - 1);
        int m0 = t >> 7;                  // wave-uniform (0 or 1)
        const int fc = f >> 3, fe = (f & 7) * 2;
        float a0 = 0.f, a1 = 0.f;
        for (int n = 0; n < NN; n++) {
            const ushort_t* xp = (const ushort_t*)(u1buf + n * 256 + ((fc ^ (n & 15)) << 4) + fe);
            float xv = bf2f(*xp);
            float4 e4 = *(const float4*)&ew_s[n * NM];
            float e0 = m0 ? e4.y : e4.x;
            float e1 = m0 ? e4.w : e4.z;
            a0 += e0 * xv;
            a1 += e1 * xv;
        }
        xw[m0][f]     = a0 * winv[m0];
        xw[m0 + 2][f] = a1 * winv[m0 + 2];
    }

    // ======== h_nei A-fragments (read xsf BEFORE the overwrite barrier) ========
    short8v afr[4];
    {
        const int row = wave * 16 + (lane & 15);
        const int sub = lane >> 4;
#pragma unroll
        for (int ks = 0; ks < 4; ks++) {
            int c = ks * 4 + sub;
            afr[ks] = *(const short8v*)(u1buf + row * 256 + ((c ^ (row & 15)) << 4));
        }
    }
    __syncthreads();   // all xsf readers (xw + afr) done; xw visible below

    // ======== h_nei = xsf @ W0 + bv_emb[0] via MFMA; D -> hns (overlays xsf) ========
    {
        const int n0 = wave * 16;
        const int colb = lane & 15;
        const int rsub = lane >> 4;
#pragma unroll
        for (int ct = 0; ct < 4; ct++) {
            float bias = P.bv_emb[ct * 16 + colb];
            f32x4 c = {bias, bias, bias, bias};
#pragma unroll
            for (int ks = 0; ks < 4; ks++) {
                short8v bhi = ld_frag(P.wsf + (size_t)(ks * 4 + ct) * 64 + lane);
                short8v blo = ld_frag(P.wsf + 1024 + (size_t)(ks * 4 + ct) * 64 + lane);
                c = MFMA16(afr[ks], bhi, c);
                c = MFMA16(afr[ks], blo, c);
            }
#pragma unroll
            for (int e = 0; e < 4; e++) {
                int n = n0 + rsub * 4 + e;
                int d = ct * 16 + colb;
                *(float*)(u1buf + n * 256 + ((((d >> 2) ^ (n & 15))) << 4) + (d & 3) * 4) = c[e];
            }
        }
    }

    // ======== per_view_ctx: hv = xw@Wv_emb[m] + s*bv_emb ; pvc = hv@Wv_val[m] ========
    {
        int m = wave, d = lane;
        float a0 = wssum[m] * P.bv_emb[m * ND + d], a1 = 0.f;
        const float* We = P.Wv_emb + (size_t)m * NF * ND;
        for (int f = 0; f < NF; f += 2) {
            a0 += xw[m][f] * We[f * ND + d];
            a1 += xw[m][f + 1] * We[(f + 1) * ND + d];
        }
        hv[m][d] = a0 + a1;
    }
    __syncthreads();
    {
        int m = wave, d = lane;
        float a0 = wssum[m] * P.bv_val[m * ND + d], a1 = 0.f;
        const float* Wv = P.Wv_val + (size_t)m * ND * ND;
        for (int k = 0; k < ND; k += 2) {
            a0 += hv[m][k] * Wv[k * ND + d];
            a1 += hv[m][k + 1] * Wv[(k + 1) * ND + d];
        }
        pvc[m][d] = a0 + a1;
    }
    __syncthreads();

    // ======== ctx_vec + h_anc reduce ========
    if (t < ND) {
        sA[t] = 0.25f * (pvc[0][t] + pvc[1][t] + pvc[2][t] + pvc[3][t]);
        xcur[t] = P.b_anc[t] + part_a[0][t] + part_a[1][t] + part_a[2][t] + part_a[3][t];
    }
    __syncthreads();

    // ======== r-MLP: wave-split-K partials + 1-wave reduce phases ========
    {   // Win: 128-k, wave quarter 32
        const float* xin = (wave < 2) ? (ga + wave * 32) : (sA + (wave - 2) * 32);
        const float* Wr = P.r_Win + (wave * 32) * NHID + lane;
        float a0 = 0.f, a1 = 0.f;
#pragma unroll
        for (int i = 0; i < 32; i += 2) {
            a0 += xin[i] * Wr[i * NHID];
            a1 += xin[i + 1] * Wr[(i + 1) * NHID];
        }
        part_a[wave][lane] = a0 + a1;
    }
    __syncthreads();
    if (t < NHID) {
        float acc = P.r_bin[t] + part_a[0][t] + part_a[1][t] + part_a[2][t] + part_a[3][t];
        float mean = wsum64(acc) * (1.0f / 64.0f);
        float dv = acc - mean;
        float var = wsum64(dv * dv) * (1.0f / 64.0f);
        float xln = dv * rsqrtf(var + 1e-5f) * P.r_lng[t] + P.r_lnb[t];
        sB[t] = gelu_f(xln);
    }
    __syncthreads();
    {   // W1: 64-k, wave quarter 16
        const float* Wr = P.r_W1 + (wave * 16) * NHID + lane;
        float acc = 0.f;
#pragma unroll
        for (int i = 0; i < 16; i++) acc += sB[wave * 16 + i] * Wr[i * NHID];
        part_a[wave][lane] = acc;
    }
    __syncthreads();
    if (t < NHID)
        sA[t] = gelu_f(P.r_b1[t] + part_a[0][t] + part_a[1][t] + part_a[2][t] + part_a[3][t]);
    __syncthreads();
    {   // W2
        const float* Wr = P.r_W2 + (wave * 16) * NHID + lane;
        float acc = 0.f;
#pragma unroll
        for (int i = 0; i < 16; i++) acc += sA[wave * 16 + i] * Wr[i * NHID];
        part_a[wave][lane] = acc;
    }
    __syncthreads();
    if (t < NHID)
        hfin[t] = gelu_f(P.r_b2[t] + part_a[0][t] + part_a[1][t] + part_a[2][t] + part_a[3][t]);
    __syncthreads();

    // ======== pi (softmax over views), beta ========
    if (t < NH * NM) {
        int h = t >> 2, mm = t & 3;
        float acc = P.r_bview[h * NM + mm];
        for (int k = 0; k < NHID; k++) acc += hfin[k] * P.r_Wview[(h * NHID + k) * NM + mm];
        pi_raw[t] = acc;
    }
    if (t >= 64 && t < 64 + NH) {
        int h = t - 64;
        float acc = P.r_bmode[h];
        for (int k = 0; k < NHID; k++) acc += hfin[k] * P.r_Wmode[h * NHID + k];
        beta_s[h] = 1.0f / (1.0f + expf(-acc));
    }
    __syncthreads();
    if (t < NH) {
        float mx = -1e30f;
        for (int mm = 0; mm < NM; mm++) mx = fmaxf(mx, pi_raw[t * NM + mm]);
        float s = 0.f, e[NM];
        for (int mm = 0; mm < NM; mm++) { e[mm] = expf(pi_raw[t * NM + mm] - mx); s += e[mm]; }
        for (int mm = 0; mm < NM; mm++) pi_s[t][mm] = e[mm] / s;
    }
    __syncthreads();

    // ======== gate[h][n] = log(sum_m pi[h,m]*ew_raw[n,m] + EPS) ========
    {
        int h = wave, n = lane;
        float wv = 0.f;
        for (int mm = 0; mm < NM; mm++) wv += pi_s[h][mm] * ew_s[n * NM + mm];
        gate_s[h][n] = logf(wv + EPSC);
    }
    __syncthreads();

    // ======== attention + FF layers ========
    const float inv_tau_scale = 0.25f / expf(P.log_tau[wave]);  // scale=1/sqrt(16)
    for (int l = 0; l < NLAYER; l++) {
        const float* Wq  = P.L_Wq  + l * ND * ND;
        const float* Wo  = P.L_Wo  + l * ND * ND;
        const float* ln1g = P.L_ln1g + l * ND;
        const float* ln1b = P.L_ln1b + l * ND;
        const float* ln2g = P.L_ln2g + l * ND;
        const float* ln2b = P.L_ln2b + l * ND;
        const float* Wf1 = P.L_Wf1 + l * ND * NFF;
        const float* bf1 = P.L_bf1 + l * NFF;
        const float* Wf2 = P.L_Wf2 + l * NFF * ND;
        const float* bf2 = P.L_bf2 + l * ND;

        // qv: wave h computes its own 16 q values, 4-lane k-split (in-wave, no barrier)
        {
            int j = lane >> 2, kc = lane & 3;
            float acc = 0.f;
#pragma unroll
            for (int i = 0; i < 16; i++) {
                int k = kc * 16 + i;
                acc += xcur[k] * Wq[k * ND + wave * 16 + j];
            }
            acc += __shfl_xor(acc, 1, 64);
            acc += __shfl_xor(acc, 2, 64);
            if (kc == 0) qv[wave * 16 + j] = acc;
        }
        // ---- K/V projections via MFMA (unchanged) ----
        {
            const int n0 = wave * 16;
            const int row = n0 + (lane & 15);
            const int rsub = lane >> 4;
            short8v ahi[2], alo[2];
#pragma unroll
            for (int ks = 0; ks < 2; ks++) {
                int c0 = ks * 8 + rsub * 2;
                f32x4 x0 = *(const f32x4*)(u1buf + row * 256 + ((c0 ^ (row & 15)) << 4));
                f32x4 x1 = *(const f32x4*)(u1buf + row * 256 + (((c0 + 1) ^ (row & 15)) << 4));
                union { ushort_t u[8]; short8v v; } uh, ul;
#pragma unroll
                for (int i = 0; i < 8; i++) {
                    float w = (i < 4) ? x0[i] : x1[i - 4];
                    ushort_t h = f2bf(w);
                    uh.u[i] = h;
                    ul.u[i] = f2bf(w - bf2f(h));
                }
                ahi[ks] = uh.v; alo[ks] = ul.v;
            }
            const uint4* bbase = P.wsf + 2048 + (size_t)(l * 2) * 1024;
#pragma unroll
            for (int mat = 0; mat < 2; mat++) {           // 0 = K, 1 = V
                const uint4* bb = bbase + (size_t)mat * 1024;
                __hip_bfloat16* dst = mat ? &vb16[0][0] : &kb16[0][0];
#pragma unroll
                for (int ct = 0; ct < 4; ct++) {
                    f32x4 c = {0.f, 0.f, 0.f, 0.f};
#pragma unroll
                    for (int ks = 0; ks < 2; ks++) {
                        short8v bhi = ld_frag(bb + (size_t)(ks * 4 + ct) * 64 + lane);
                        short8v blo = ld_frag(bb + 512 + (size_t)(ks * 4 + ct) * 64 + lane);
                        c = MFMA16(ahi[ks], bhi, c);
                        c = MFMA16(ahi[ks], blo, c);
                        c = MFMA16(alo[ks], bhi, c);
                    }
#pragma unroll
                    for (int e = 0; e < 4; e++) {
                        int n = n0 + rsub * 4 + e;
                        dst[n * (ND + 2) + ct * 16 + (lane & 15)] = __float2bfloat16(c[e]);
                    }
                }
            }
        }
        __syncthreads();
        // scores + softmax over n (one head per wave)
        {
            int h = wave, n = lane;
            float s = 0.f;
#pragma unroll
            for (int j = 0; j < 16; j++)
                s += qv[h * 16 + j] * __bfloat162float(kb16[n][h * 16 + j]);
            s = s * inv_tau_scale + gate_s[h][n];
            float mx = wmax64(s);
            float e = expf(s - mx);
            float se = wsum64(e);
            attn_s[h][n] = e / se;
        }
        __syncthreads();
        // PV wave-split: wave w sums n in [16w,16w+16) for all 64 d
        {
            int d = lane, h = d >> 4;
            float acc = 0.f;
#pragma unroll
            for (int i = 0; i < 16; i++) {
                int n = wave * 16 + i;
                acc += attn_s[h][n] * __bfloat162float(vb16[n][d]);
            }
            part_b[wave][d] = acc;
        }
        __syncthreads();
        // Wo wave-split: wave w handles c in [16w,16w+16); ctx via broadcast reduce
        {
            int d = lane;
            float acc = 0.f;
#pragma unroll
            for (int i = 0; i < 16; i++) {
                int c = wave * 16 + i;
                float ctxc = part_b[0][c] + part_b[1][c] + part_b[2][c] + part_b[3][c];
                acc += ctxc * Wo[c * ND + d];
            }
            part_c[wave][d] = acc;
        }
        __syncthreads();
        if (t < ND) {
            float xv = xcur[t] + part_c[0][t] + part_c[1][t] + part_c[2][t] + part_c[3][t];
            float mean = wsum64(xv) * (1.0f / 64.0f);
            float dv = xv - mean;
            float var = wsum64(dv * dv) * (1.0f / 64.0f);
            xcur[t] = dv * rsqrtf(var + 1e-5f) * ln1g[t] + ln1b[t];
        }
        __syncthreads();
        // FF1: 2-lane k-split in-wave (j = t>>1 stays inside the wave)
        {
            int j = t >> 1, kh = t & 1;
            float acc = 0.f;
#pragma unroll
            for (int i = 0; i < 32; i++) {
                int d = kh * 32 + i;
                acc += xcur[d] * Wf1[d * NFF + j];
            }
            acc += __shfl_xor(acc, 1, 64);
            if (kh == 0) ffs[j] = gelu_f(acc + bf1[j]);
        }
        __syncthreads();
        // FF2 wave-split: wave w sums k in [32w,32w+32)
        {
            int d = lane;
            const float* Wr = Wf2 + (wave * 32) * ND + d;
            float a0 = 0.f, a1 = 0.f;
#pragma unroll
            for (int i = 0; i < 32; i += 2) {
                a0 += ffs[wave * 32 + i] * Wr[i * ND];
                a1 += ffs[wave * 32 + i + 1] * Wr[(i + 1) * ND];
            }
            part_b[wave][d] = a0 + a1;
        }
        __syncthreads();
        if (t < ND) {
            float xv = xcur[t] + bf2[t] + part_b[0][t] + part_b[1][t] + part_b[2][t] + part_b[3][t];
            float mean = wsum64(xv) * (1.0f / 64.0f);
            float dv = xv - mean;
            float var = wsum64(dv * dv) * (1.0f / 64.0f);
            xcur[t] = dv * rsqrtf(var + 1e-5f) * ln2g[t] + ln2b[t];
        }
        __syncthreads();
    }

    // ======== blended + final head ========
    if (t < ND) {
        float acc = 0.f;
#pragma unroll
        for (int h = 0; h < NH; h++) {
            float iso = 0.f;
#pragma unroll
            for (int mm = 0; mm < NM; mm++) iso += pi_s[h][mm] * pvc[mm][t];
            acc += (1.0f - beta_s[h]) * iso + beta_s[h] * xcur[t];
        }
        float bl = acc * 0.25f;
        float mean = wsum64(bl) * (1.0f / 64.0f);
        float dv = bl - mean;
        float var = wsum64(dv * dv) * (1.0f / 64.0f);
        sA[t] = dv * rsqrtf(var + 1e-5f) * P.p_lng[t] + P.p_lnb[t];
    }
    __syncthreads();
    // p_W1: 8-way k-split across all 256 threads
    {
        int o = lane & 31;
        int kp = wave * 2 + (lane >> 5);   // 0..7
        const float* Wr = P.p_W1 + (kp * 8) * 32 + o;
        float acc = 0.f;
#pragma unroll
        for (int i = 0; i < 8; i++) acc += sA[kp * 8 + i] * Wr[i * 32];
        ((float*)part_b)[kp * 32 + o] = acc;
    }
    __syncthreads();
    if (t < 32) {
        float acc = P.p_b1[t];
#pragma unroll
        for (int kp = 0; kp < 8; kp++) acc += ((float*)part_b)[kp * 32 + t];
        sB[t] = gelu_f(acc);
    }
    __syncthreads();
    if (t < NOUT * 8) {   // t<64: o = t>>3, kc = t&7 (in-wave 8-lane groups)
        int o = t >> 3, kc = t & 7;
        float acc = 0.f;
#pragma unroll
        for (int i = 0; i < 4; i++) acc += sB[kc * 4 + i] * P.p_W2[(kc * 4 + i) * NOUT + o];
        acc += __shfl_xor(acc, 1, 64);
        acc += __shfl_xor(acc, 2, 64);
        acc += __shfl_xor(acc, 4, 64);
        if (kc == 0) P.out[(size_t)b * NOUT + o] = acc + P.p_b2[o];
    }
}

extern "C" void kernel_launch(void* const* d_in, const int* in_sizes, int n_in,
                              void* d_out, int out_size, void* d_ws, size_t ws_size,
                              hipStream_t stream)
{
    (void)in_sizes; (void)n_in; (void)ws_size; (void)out_size;
    GParams P;
    P.x_anc   = (const float*)d_in[0];
    P.g_anc   = (const float*)d_in[1];
    P.x_nei   = (const float*)d_in[2];
    P.ew_anc  = (const float*)d_in[3];
    P.W_anc   = (const float*)d_in[4];
    P.b_anc   = (const float*)d_in[5];
    P.Wv_emb  = (const float*)d_in[6];
    P.bv_emb  = (const float*)d_in[7];
    P.Wv_val  = (const float*)d_in[8];
    P.bv_val  = (const float*)d_in[9];
    P.r_Win   = (const float*)d_in[10];
    P.r_bin   = (const float*)d_in[11];
    P.r_lng   = (const float*)d_in[12];
    P.r_lnb   = (const float*)d_in[13];
    P.r_W1    = (const float*)d_in[14];
    P.r_b1    = (const float*)d_in[15];
    P.r_W2    = (const float*)d_in[16];
    P.r_b2    = (const float*)d_in[17];
    P.r_Wview = (const float*)d_in[18];
    P.r_bview = (const float*)d_in[19];
    P.r_Wmode = (const float*)d_in[20];
    P.r_bmode = (const float*)d_in[21];
    P.log_tau = (const float*)d_in[22];
    P.L_Wq    = (const float*)d_in[23];
    P.L_Wk    = (const float*)d_in[24];
    P.L_Wv    = (const float*)d_in[25];
    P.L_Wo    = (const float*)d_in[26];
    P.L_ln1g  = (const float*)d_in[27];
    P.L_ln1b  = (const float*)d_in[28];
    P.L_ln2g  = (const float*)d_in[29];
    P.L_ln2b  = (const float*)d_in[30];
    P.L_Wf1   = (const float*)d_in[31];
    P.L_bf1   = (const float*)d_in[32];
    P.L_Wf2   = (const float*)d_in[33];
    P.L_bf2   = (const float*)d_in[34];
    P.p_lng   = (const float*)d_in[35];
    P.p_lnb   = (const float*)d_in[36];
    P.p_W1    = (const float*)d_in[37];
    P.p_b1    = (const float*)d_in[38];
    P.p_W2    = (const float*)d_in[39];
    P.p_b2    = (const float*)d_in[40];
    P.wsf     = (const uint4*)d_ws;
    P.out     = (float*)d_out;
    hipLaunchKernelGGL(prep_w, dim3(12), dim3(256), 0, stream,
                       P.Wv_emb, P.L_Wk, P.L_Wv, (uint4*)d_ws);
    hipLaunchKernelGGL(gora_fused, dim3(NB), dim3(256), 0, stream, P);
}

// Round 7
// 454.844 us; speedup vs baseline: 1.1557x; 1.1557x over previous
//
#include <hip/hip_runtime.h>
#include <hip/hip_bf16.h>
#include <math.h>

#define NB 4096
#define NN 64
#define NM 4
#define NF 128
#define NOBS 64
#define ND 64
#define NH 4
#define NLAYER 2
#define NFF 128
#define NHID 64
#define NOUT 8
#define EPSC 1e-6f

typedef unsigned short ushort_t;
typedef __attribute__((ext_vector_type(8))) short short8v;   // 8 bf16 (4 VGPR) MFMA A/B frag
typedef __attribute__((ext_vector_type(4))) float f32x4;     // MFMA C/D frag

#define MFMA16(a, b, c) __builtin_amdgcn_mfma_f32_16x16x32_bf16((a), (b), (c), 0, 0, 0)

struct GParams {
    const float* x_anc; const float* g_anc; const float* x_nei; const float* ew_anc;
    const float* W_anc; const float* b_anc;
    const float* Wv_emb; const float* bv_emb; const float* Wv_val; const float* bv_val;
    const float* r_Win; const float* r_bin; const float* r_lng; const float* r_lnb;
    const float* r_W1; const float* r_b1; const float* r_W2; const float* r_b2;
    const float* r_Wview; const float* r_bview; const float* r_Wmode; const float* r_bmode;
    const float* log_tau;
    const float* L_Wq; const float* L_Wk; const float* L_Wv; const float* L_Wo;
    const float* L_ln1g; const float* L_ln1b; const float* L_ln2g; const float* L_ln2b;
    const float* L_Wf1; const float* L_bf1; const float* L_Wf2; const float* L_bf2;
    const float* p_lng; const float* p_lnb; const float* p_W1; const float* p_b1;
    const float* p_W2; const float* p_b2;
    const uint4* wsf;     // prepped split-bf16 weight fragments (see prep_w)
    float* out;
};

__device__ __forceinline__ float gelu_f(float x) {
    return 0.5f * x * (1.0f + erff(x * 0.7071067811865476f));
}
__device__ __forceinline__ float wsum64(float v) {
#pragma unroll
    for (int off = 32; off > 0; off >>= 1) v += __shfl_xor(v, off, 64);
    return v;
}
__device__ __forceinline__ float wmax64(float v) {
#pragma unroll
    for (int off = 32; off > 0; off >>= 1) v = fmaxf(v, __shfl_xor(v, off, 64));
    return v;
}
__device__ __forceinline__ float bf2f(ushort_t u) {
    union { unsigned int i; float f; } c; c.i = ((unsigned int)u) << 16; return c.f;
}
__device__ __forceinline__ ushort_t f2bf(float f) {
    __hip_bfloat16 h = __float2bfloat16(f);
    ushort_t u; __builtin_memcpy(&u, &h, 2); return u;
}
__device__ __forceinline__ short8v ld_frag(const uint4* p) {
    union { uint4 q; short8v v; } u; u.q = *p; return u.v;
}

// ---------------------------------------------------------------------------
// Weight prep (unchanged): split-bf16 MFMA B-fragments in d_ws.
// ---------------------------------------------------------------------------
__global__ void prep_w(const float* Wv_emb, const float* L_Wk, const float* L_Wv, uint4* ws)
{
    int task = blockIdx.x * 256 + threadIdx.x;    // 48 frags * 64 lanes = 3072
    if (task >= 3072) return;
    int lane = task & 63;
    int frag = task >> 6;                         // 0..47
    const float* src; int ks, ct; uint4 *dhi, *dlo;
    if (frag < 16) {                              // W0
        ks = frag >> 2; ct = frag & 3;
        src = Wv_emb;
        dhi = ws + (size_t)frag * 64 + lane;
        dlo = ws + 1024 + (size_t)frag * 64 + lane;
    } else {
        int g = frag - 16;                        // 0..31
        int matidx = g >> 3;                      // 0=K0 1=V0 2=K1 3=V1
        int fi = g & 7;
        ks = fi >> 2; ct = fi & 3;                // ks in {0,1}
        src = ((matidx & 1) ? L_Wv : L_Wk) + (size_t)(matidx >> 1) * (ND * ND);
        dhi = ws + 2048 + (size_t)matidx * 1024 + (size_t)fi * 64 + lane;
        dlo = dhi + 512;
    }
    union { ushort_t u[8]; uint4 q; } hi, lo;
#pragma unroll
    for (int i = 0; i < 8; i++) {
        int k = ks * 32 + (lane >> 4) * 8 + i;
        int d = ct * 16 + (lane & 15);
        float w = src[k * ND + d];
        ushort_t h = f2bf(w);
        hi.u[i] = h;
        lo.u[i] = f2bf(w - bf2f(h));
    }
    *dhi = hi.q;
    *dlo = lo.q;
}

// launch_bounds notes (measured): (256,4) clamps to 64 VGPR -> spills (662us);
// (256,2) only 2 blocks resident; (256,3) = 3 blocks/CU, no spill -> best.
// Round-5 lesson: cross-wave K-split of sequential matvecs REGRESSED (245->347us,
// scratch writes 7.8MB) — TLP from 3 resident blocks already covers idle waves;
// the win is deeper per-thread load ILP (4 accumulators), not more barriers.
__global__ __launch_bounds__(256, 3)
void gora_fused(GParams P)
{
    const int b = blockIdx.x;
    const int t = threadIdx.x;
    const int lane = t & 63;
    const int wave = t >> 6;

    // ---- LDS ~43.5 KB -> 3 blocks/CU ----
    __shared__ alignas(16) char u1buf[NN * NF * 2];  // 16 KB: xsf bf16 then hns f32 (swizzled)
    __shared__ float hv[NM][ND];
    __shared__ __hip_bfloat16 kb16[NN][ND + 2];      // 8.25KB K (padded rows: 66 elems)
    __shared__ __hip_bfloat16 vb16[NN][ND + 2];      // 8.25KB V
    __shared__ float ew_s[NN * NM];                  // raw masked ew  [n*4+m]
    __shared__ float winv[NM], wssum[NM];
    __shared__ float xa[NF];
    __shared__ float ga[NOBS];
    __shared__ float xw[NM][NF];
    __shared__ float pvc[NM][ND];
    __shared__ float hfin[NHID];
    __shared__ float pi_raw[NH * NM];
    __shared__ float pi_s[NH][NM];
    __shared__ float beta_s[NH];
    __shared__ float gate_s[NH][NN];
    __shared__ float xcur[ND];
    __shared__ float qv[ND];
    __shared__ float attn_s[NH][NN];
    __shared__ float ctx_s[ND];
    __shared__ float ffs[NFF];
    __shared__ float sA[ND];
    __shared__ float sB[ND];

    // ================= loads =================
    {
        float e = P.ew_anc[(size_t)b * NN * NM + t];   // 256 = N*M exactly
        ew_s[t] = (e > 0.0f) ? e : 0.0f;               // ew * (ew>0)
    }
    if (t < NF) xa[t] = P.x_anc[(size_t)b * NF + t];
    else if (t < NF + NOBS) ga[t - NF] = P.g_anc[(size_t)b * NOBS + (t - NF)];
    {
        // xsf swizzled store: elem (n,f) byte = n*256 + ((f>>3 ^ (n&15))<<4) + (f&7)*2
        const float4* xn4 = (const float4*)(P.x_nei + (size_t)b * NN * NF);
#pragma unroll
        for (int i = 0; i < 8; i++) {
            int i4 = t + i * 256;                      // 2048 float4 total
            float4 v4 = xn4[i4];
            __hip_bfloat162 p0, p1;
            p0.x = __float2bfloat16(v4.x); p0.y = __float2bfloat16(v4.y);
            p1.x = __float2bfloat16(v4.z); p1.y = __float2bfloat16(v4.w);
            int n = i4 >> 5;
            int c = (i4 >> 1) & 15;
            char* dstb = u1buf + n * 256 + ((c ^ (n & 15)) << 4) + (i4 & 1) * 8;
            ((__hip_bfloat162*)dstb)[0] = p0;
            ((__hip_bfloat162*)dstb)[1] = p1;
        }
    }
    __syncthreads();

    // ======== view-weight norms (t<4) + h_anc (t in [64,128)) ========
    if (t < NM) {
        float s = 0.0f;
        for (int n = 0; n < NN; n++) s += ew_s[n * NM + t];
        float c = fmaxf(s, EPSC);
        winv[t]  = 1.0f / c;
        wssum[t] = s / c;
    }
    if (t >= 64 && t < 128) {
        int d = t - 64;
        float a0 = P.b_anc[d], a1 = 0.f, a2 = 0.f, a3 = 0.f;
#pragma unroll
        for (int f = 0; f < NF; f += 4) {
            a0 += xa[f]     * P.W_anc[f * ND + d];
            a1 += xa[f + 1] * P.W_anc[(f + 1) * ND + d];
            a2 += xa[f + 2] * P.W_anc[(f + 2) * ND + d];
            a3 += xa[f + 3] * P.W_anc[(f + 3) * ND + d];
        }
        xcur[d] = (a0 + a1) + (a2 + a3);  // x = h_anc
    }
    __syncthreads();

    // ======== xw[m][f] = sum_n w[m,n] * x_nei[n,f]  (swizzled xsf reads) ========
    {
        int f = t & (NF - 1);
        int m0 = t >> 7;                  // wave-uniform (0 or 1)
        const int fc = f >> 3, fe = (f & 7) * 2;
        float a0 = 0.f, a1 = 0.f;
        for (int n = 0; n < NN; n++) {
            const ushort_t* xp = (const ushort_t*)(u1buf + n * 256 + ((fc ^ (n & 15)) << 4) + fe);
            float xv = bf2f(*xp);
            a0 += ew_s[n * NM + m0] * xv;
            a1 += ew_s[n * NM + m0 + 2] * xv;
        }
        xw[m0][f]     = a0 * winv[m0];
        xw[m0 + 2][f] = a1 * winv[m0 + 2];
    }

    // ======== h_nei A-fragments (read xsf BEFORE the overwrite barrier) ========
    short8v afr[4];
    {
        const int row = wave * 16 + (lane & 15);
        const int sub = lane >> 4;
#pragma unroll
        for (int ks = 0; ks < 4; ks++) {
            int c = ks * 4 + sub;
            afr[ks] = *(const short8v*)(u1buf + row * 256 + ((c ^ (row & 15)) << 4));
        }
    }
    __syncthreads();   // all xsf readers (xw + afr) done; xw visible below

    // ======== h_nei = xsf @ W0 + bv_emb[0] via MFMA; D -> hns (overlays xsf) ========
    {
        const int n0 = wave * 16;
        const int colb = lane & 15;
        const int rsub = lane >> 4;
#pragma unroll
        for (int ct = 0; ct < 4; ct++) {
            float bias = P.bv_emb[ct * 16 + colb];
            f32x4 c = {bias, bias, bias, bias};
#pragma unroll
            for (int ks = 0; ks < 4; ks++) {
                short8v bhi = ld_frag(P.wsf + (size_t)(ks * 4 + ct) * 64 + lane);
                short8v blo = ld_frag(P.wsf + 1024 + (size_t)(ks * 4 + ct) * 64 + lane);
                c = MFMA16(afr[ks], bhi, c);
                c = MFMA16(afr[ks], blo, c);
            }
#pragma unroll
            for (int e = 0; e < 4; e++) {
                int n = n0 + rsub * 4 + e;
                int d = ct * 16 + colb;
                *(float*)(u1buf + n * 256 + ((((d >> 2) ^ (n & 15))) << 4) + (d & 3) * 4) = c[e];
            }
        }
    }

    // ======== per_view_ctx: hv = xw@Wv_emb[m] + s*bv_emb ; pvc = hv@Wv_val[m] ========
    {
        int m = wave, d = lane;
        float a0 = wssum[m] * P.bv_emb[m * ND + d], a1 = 0.f, a2 = 0.f, a3 = 0.f;
        const float* We = P.Wv_emb + (size_t)m * NF * ND;
#pragma unroll
        for (int f = 0; f < NF; f += 4) {
            a0 += xw[m][f]     * We[f * ND + d];
            a1 += xw[m][f + 1] * We[(f + 1) * ND + d];
            a2 += xw[m][f + 2] * We[(f + 2) * ND + d];
            a3 += xw[m][f + 3] * We[(f + 3) * ND + d];
        }
        hv[m][d] = (a0 + a1) + (a2 + a3);
    }
    __syncthreads();
    {
        int m = wave, d = lane;
        float a0 = wssum[m] * P.bv_val[m * ND + d], a1 = 0.f, a2 = 0.f, a3 = 0.f;
        const float* Wv = P.Wv_val + (size_t)m * ND * ND;
#pragma unroll
        for (int k = 0; k < ND; k += 4) {
            a0 += hv[m][k]     * Wv[k * ND + d];
            a1 += hv[m][k + 1] * Wv[(k + 1) * ND + d];
            a2 += hv[m][k + 2] * Wv[(k + 2) * ND + d];
            a3 += hv[m][k + 3] * Wv[(k + 3) * ND + d];
        }
        pvc[m][d] = (a0 + a1) + (a2 + a3);
    }
    __syncthreads();

    // ======== ctx_vec + r-MLP ========
    if (t < ND) sA[t] = 0.25f * (pvc[0][t] + pvc[1][t] + pvc[2][t] + pvc[3][t]);
    __syncthreads();
    if (t < NHID) {
        float a0 = P.r_bin[t], a1 = 0.f, a2 = 0.f, a3 = 0.f;
#pragma unroll
        for (int f = 0; f < NOBS; f += 4) {
            a0 += ga[f]     * P.r_Win[f * NHID + t];
            a1 += ga[f + 1] * P.r_Win[(f + 1) * NHID + t];
            a2 += ga[f + 2] * P.r_Win[(f + 2) * NHID + t];
            a3 += ga[f + 3] * P.r_Win[(f + 3) * NHID + t];
        }
#pragma unroll
        for (int f = 0; f < ND; f += 4) {
            a0 += sA[f]     * P.r_Win[(NOBS + f) * NHID + t];
            a1 += sA[f + 1] * P.r_Win[(NOBS + f + 1) * NHID + t];
            a2 += sA[f + 2] * P.r_Win[(NOBS + f + 2) * NHID + t];
            a3 += sA[f + 3] * P.r_Win[(NOBS + f + 3) * NHID + t];
        }
        float acc = (a0 + a1) + (a2 + a3);
        float mean = wsum64(acc) * (1.0f / 64.0f);
        float dv = acc - mean;
        float var = wsum64(dv * dv) * (1.0f / 64.0f);
        float xln = dv * rsqrtf(var + 1e-5f) * P.r_lng[t] + P.r_lnb[t];
        sB[t] = gelu_f(xln);
    }
    __syncthreads();
    if (t < NHID) {
        float a0 = P.r_b1[t], a1 = 0.f, a2 = 0.f, a3 = 0.f;
#pragma unroll
        for (int k = 0; k < NHID; k += 4) {
            a0 += sB[k]     * P.r_W1[k * NHID + t];
            a1 += sB[k + 1] * P.r_W1[(k + 1) * NHID + t];
            a2 += sB[k + 2] * P.r_W1[(k + 2) * NHID + t];
            a3 += sB[k + 3] * P.r_W1[(k + 3) * NHID + t];
        }
        sA[t] = gelu_f((a0 + a1) + (a2 + a3));
    }
    __syncthreads();
    if (t < NHID) {
        float a0 = P.r_b2[t], a1 = 0.f, a2 = 0.f, a3 = 0.f;
#pragma unroll
        for (int k = 0; k < NHID; k += 4) {
            a0 += sA[k]     * P.r_W2[k * NHID + t];
            a1 += sA[k + 1] * P.r_W2[(k + 1) * NHID + t];
            a2 += sA[k + 2] * P.r_W2[(k + 2) * NHID + t];
            a3 += sA[k + 3] * P.r_W2[(k + 3) * NHID + t];
        }
        hfin[t] = gelu_f((a0 + a1) + (a2 + a3));
    }
    __syncthreads();

    // ======== pi / beta: in-wave K-split (no extra barriers, no LDS partials) ========
    if (t < 64) {                       // wave 0: pi_raw = hfin @ r_Wview, 16 outs x 4-way K-split
        int out = lane & 15;
        int h = out >> 2, mm = out & 3;
        int kq = lane >> 4;             // 0..3
        float a0 = 0.f, a1 = 0.f;
#pragma unroll
        for (int i = 0; i < 16; i += 2) {
            int k = kq * 16 + i;
            a0 += hfin[k]     * P.r_Wview[(h * NHID + k) * NM + mm];
            a1 += hfin[k + 1] * P.r_Wview[(h * NHID + k + 1) * NM + mm];
        }
        float acc = a0 + a1;
        acc += __shfl_xor(acc, 16, 64);
        acc += __shfl_xor(acc, 32, 64);
        if (kq == 0) pi_raw[out] = acc + P.r_bview[h * NM + mm];
    } else if (t < 128) {               // wave 1: beta = sigmoid(hfin @ r_Wmode), 4 outs x 16-way
        int h = lane >> 4;
        int kq = lane & 15;
        float acc = 0.f;
#pragma unroll
        for (int i = 0; i < 4; i++) {
            int k = kq * 4 + i;
            acc += hfin[k] * P.r_Wmode[h * NHID + k];
        }
        acc += __shfl_xor(acc, 1, 64);
        acc += __shfl_xor(acc, 2, 64);
        acc += __shfl_xor(acc, 4, 64);
        acc += __shfl_xor(acc, 8, 64);
        if (kq == 0) beta_s[h] = 1.0f / (1.0f + expf(-(acc + P.r_bmode[h])));
    }
    __syncthreads();
    if (t < NH) {
        float mx = -1e30f;
        for (int mm = 0; mm < NM; mm++) mx = fmaxf(mx, pi_raw[t * NM + mm]);
        float s = 0.f, e[NM];
        for (int mm = 0; mm < NM; mm++) { e[mm] = expf(pi_raw[t * NM + mm] - mx); s += e[mm]; }
        for (int mm = 0; mm < NM; mm++) pi_s[t][mm] = e[mm] / s;
    }
    __syncthreads();

    // ======== gate[h][n] = log(sum_m pi[h,m]*ew_raw[n,m] + EPS) ========
    {
        int h = wave, n = lane;
        float wv = 0.f;
        for (int mm = 0; mm < NM; mm++) wv += pi_s[h][mm] * ew_s[n * NM + mm];
        gate_s[h][n] = logf(wv + EPSC);
    }
    __syncthreads();

    // ======== attention + FF layers ========
    const float inv_tau_scale = 0.25f / expf(P.log_tau[wave]);  // scale=1/sqrt(16)
    for (int l = 0; l < NLAYER; l++) {
        const float* Wq  = P.L_Wq  + l * ND * ND;
        const float* Wo  = P.L_Wo  + l * ND * ND;
        const float* ln1g = P.L_ln1g + l * ND;
        const float* ln1b = P.L_ln1b + l * ND;
        const float* ln2g = P.L_ln2g + l * ND;
        const float* ln2b = P.L_ln2b + l * ND;
        const float* Wf1 = P.L_Wf1 + l * ND * NFF;
        const float* bf1 = P.L_bf1 + l * NFF;
        const float* Wf2 = P.L_Wf2 + l * NFF * ND;
        const float* bf2 = P.L_bf2 + l * ND;

        if (t < ND) {
            float a0 = 0.f, a1 = 0.f, a2 = 0.f, a3 = 0.f;
#pragma unroll
            for (int k = 0; k < ND; k += 4) {
                a0 += xcur[k]     * Wq[k * ND + t];
                a1 += xcur[k + 1] * Wq[(k + 1) * ND + t];
                a2 += xcur[k + 2] * Wq[(k + 2) * ND + t];
                a3 += xcur[k + 3] * Wq[(k + 3) * ND + t];
            }
            qv[t] = (a0 + a1) + (a2 + a3);
        }
        // ---- K/V projections via MFMA (unchanged) ----
        {
            const int n0 = wave * 16;
            const int row = n0 + (lane & 15);
            const int rsub = lane >> 4;
            short8v ahi[2], alo[2];
#pragma unroll
            for (int ks = 0; ks < 2; ks++) {
                int c0 = ks * 8 + rsub * 2;
                f32x4 x0 = *(const f32x4*)(u1buf + row * 256 + ((c0 ^ (row & 15)) << 4));
                f32x4 x1 = *(const f32x4*)(u1buf + row * 256 + (((c0 + 1) ^ (row & 15)) << 4));
                union { ushort_t u[8]; short8v v; } uh, ul;
#pragma unroll
                for (int i = 0; i < 8; i++) {
                    float w = (i < 4) ? x0[i] : x1[i - 4];
                    ushort_t h = f2bf(w);
                    uh.u[i] = h;
                    ul.u[i] = f2bf(w - bf2f(h));
                }
                ahi[ks] = uh.v; alo[ks] = ul.v;
            }
            const uint4* bbase = P.wsf + 2048 + (size_t)(l * 2) * 1024;
#pragma unroll
            for (int mat = 0; mat < 2; mat++) {           // 0 = K, 1 = V
                const uint4* bb = bbase + (size_t)mat * 1024;
                __hip_bfloat16* dst = mat ? &vb16[0][0] : &kb16[0][0];
#pragma unroll
                for (int ct = 0; ct < 4; ct++) {
                    f32x4 c = {0.f, 0.f, 0.f, 0.f};
#pragma unroll
                    for (int ks = 0; ks < 2; ks++) {
                        short8v bhi = ld_frag(bb + (size_t)(ks * 4 + ct) * 64 + lane);
                        short8v blo = ld_frag(bb + 512 + (size_t)(ks * 4 + ct) * 64 + lane);
                        c = MFMA16(ahi[ks], bhi, c);
                        c = MFMA16(ahi[ks], blo, c);
                        c = MFMA16(alo[ks], bhi, c);
                    }
#pragma unroll
                    for (int e = 0; e < 4; e++) {
                        int n = n0 + rsub * 4 + e;
                        dst[n * (ND + 2) + ct * 16 + (lane & 15)] = __float2bfloat16(c[e]);
                    }
                }
            }
        }
        __syncthreads();
        // scores + softmax over n (one head per wave); K read as 8x bf16x2
        {
            int h = wave, n = lane;
            const __hip_bfloat162* kp = (const __hip_bfloat162*)&kb16[n][h * 16];
            float s = 0.f;
#pragma unroll
            for (int j = 0; j < 8; j++) {
                float2 kf = __bfloat1622float2(kp[j]);
                s += qv[h * 16 + 2 * j] * kf.x + qv[h * 16 + 2 * j + 1] * kf.y;
            }
            s = s * inv_tau_scale + gate_s[h][n];
            float mx = wmax64(s);
            float e = expf(s - mx);
            float se = wsum64(e);
            attn_s[h][n] = e / se;
        }
        __syncthreads();
        if (t < ND) {
            int h = t >> 4;
            float a0 = 0.f, a1 = 0.f, a2 = 0.f, a3 = 0.f;
#pragma unroll
            for (int n = 0; n < NN; n += 4) {
                a0 += attn_s[h][n]     * __bfloat162float(vb16[n][t]);
                a1 += attn_s[h][n + 1] * __bfloat162float(vb16[n + 1][t]);
                a2 += attn_s[h][n + 2] * __bfloat162float(vb16[n + 2][t]);
                a3 += attn_s[h][n + 3] * __bfloat162float(vb16[n + 3][t]);
            }
            ctx_s[t] = (a0 + a1) + (a2 + a3);
        }
        __syncthreads();
        if (t < ND) {
            float a0 = 0.f, a1 = 0.f, a2 = 0.f, a3 = 0.f;
#pragma unroll
            for (int c = 0; c < ND; c += 4) {
                a0 += ctx_s[c]     * Wo[c * ND + t];
                a1 += ctx_s[c + 1] * Wo[(c + 1) * ND + t];
                a2 += ctx_s[c + 2] * Wo[(c + 2) * ND + t];
                a3 += ctx_s[c + 3] * Wo[(c + 3) * ND + t];
            }
            float xv = xcur[t] + (a0 + a1) + (a2 + a3);
            float mean = wsum64(xv) * (1.0f / 64.0f);
            float dv = xv - mean;
            float var = wsum64(dv * dv) * (1.0f / 64.0f);
            xcur[t] = dv * rsqrtf(var + 1e-5f) * ln1g[t] + ln1b[t];
        }
        __syncthreads();
        if (t < NFF) {
            float a0 = bf1[t], a1 = 0.f, a2 = 0.f, a3 = 0.f;
#pragma unroll
            for (int d = 0; d < ND; d += 4) {
                a0 += xcur[d]     * Wf1[d * NFF + t];
                a1 += xcur[d + 1] * Wf1[(d + 1) * NFF + t];
                a2 += xcur[d + 2] * Wf1[(d + 2) * NFF + t];
                a3 += xcur[d + 3] * Wf1[(d + 3) * NFF + t];
            }
            ffs[t] = gelu_f((a0 + a1) + (a2 + a3));
        }
        __syncthreads();
        if (t < ND) {
            float a0 = bf2[t], a1 = 0.f, a2 = 0.f, a3 = 0.f;
#pragma unroll
            for (int j = 0; j < NFF; j += 4) {
                a0 += ffs[j]     * Wf2[j * ND + t];
                a1 += ffs[j + 1] * Wf2[(j + 1) * ND + t];
                a2 += ffs[j + 2] * Wf2[(j + 2) * ND + t];
                a3 += ffs[j + 3] * Wf2[(j + 3) * ND + t];
            }
            float xv = xcur[t] + (a0 + a1) + (a2 + a3);
            float mean = wsum64(xv) * (1.0f / 64.0f);
            float dv = xv - mean;
            float var = wsum64(dv * dv) * (1.0f / 64.0f);
            xcur[t] = dv * rsqrtf(var + 1e-5f) * ln2g[t] + ln2b[t];
        }
        __syncthreads();
    }

    // ======== blended + final head ========
    if (t < ND) {
        float acc = 0.f;
#pragma unroll
        for (int h = 0; h < NH; h++) {
            float iso = 0.f;
#pragma unroll
            for (int mm = 0; mm < NM; mm++) iso += pi_s[h][mm] * pvc[mm][t];
            acc += (1.0f - beta_s[h]) * iso + beta_s[h] * xcur[t];
        }
        float bl = acc * 0.25f;
        float mean = wsum64(bl) * (1.0f / 64.0f);
        float dv = bl - mean;
        float var = wsum64(dv * dv) * (1.0f / 64.0f);
        sA[t] = dv * rsqrtf(var + 1e-5f) * P.p_lng[t] + P.p_lnb[t];
    }
    __syncthreads();
    if (t < 32) {
        float a0 = P.p_b1[t], a1 = 0.f, a2 = 0.f, a3 = 0.f;
#pragma unroll
        for (int d = 0; d < ND; d += 4) {
            a0 += sA[d]     * P.p_W1[d * 32 + t];
            a1 += sA[d + 1] * P.p_W1[(d + 1) * 32 + t];
            a2 += sA[d + 2] * P.p_W1[(d + 2) * 32 + t];
            a3 += sA[d + 3] * P.p_W1[(d + 3) * 32 + t];
        }
        sB[t] = gelu_f((a0 + a1) + (a2 + a3));
    }
    __syncthreads();
    if (t < NOUT) {
        float a0 = P.p_b2[t], a1 = 0.f;
#pragma unroll
        for (int j = 0; j < 32; j += 2) {
            a0 += sB[j]     * P.p_W2[j * NOUT + t];
            a1 += sB[j + 1] * P.p_W2[(j + 1) * NOUT + t];
        }
        P.out[(size_t)b * NOUT + t] = a0 + a1;
    }
}

extern "C" void kernel_launch(void* const* d_in, const int* in_sizes, int n_in,
                              void* d_out, int out_size, void* d_ws, size_t ws_size,
                              hipStream_t stream)
{
    (void)in_sizes; (void)n_in; (void)ws_size; (void)out_size;
    GParams P;
    P.x_anc   = (const float*)d_in[0];
    P.g_anc   = (const float*)d_in[1];
    P.x_nei   = (const float*)d_in[2];
    P.ew_anc  = (const float*)d_in[3];
    P.W_anc   = (const float*)d_in[4];
    P.b_anc   = (const float*)d_in[5];
    P.Wv_emb  = (const float*)d_in[6];
    P.bv_emb  = (const float*)d_in[7];
    P.Wv_val  = (const float*)d_in[8];
    P.bv_val  = (const float*)d_in[9];
    P.r_Win   = (const float*)d_in[10];
    P.r_bin   = (const float*)d_in[11];
    P.r_lng   = (const float*)d_in[12];
    P.r_lnb   = (const float*)d_in[13];
    P.r_W1    = (const float*)d_in[14];
    P.r_b1    = (const float*)d_in[15];
    P.r_W2    = (const float*)d_in[16];
    P.r_b2    = (const float*)d_in[17];
    P.r_Wview = (const float*)d_in[18];
    P.r_bview = (const float*)d_in[19];
    P.r_Wmode = (const float*)d_in[20];
    P.r_bmode = (const float*)d_in[21];
    P.log_tau = (const float*)d_in[22];
    P.L_Wq    = (const float*)d_in[23];
    P.L_Wk    = (const float*)d_in[24];
    P.L_Wv    = (const float*)d_in[25];
    P.L_Wo    = (const float*)d_in[26];
    P.L_ln1g  = (const float*)d_in[27];
    P.L_ln1b  = (const float*)d_in[28];
    P.L_ln2g  = (const float*)d_in[29];
    P.L_ln2b  = (const float*)d_in[30];
    P.L_Wf1   = (const float*)d_in[31];
    P.L_bf1   = (const float*)d_in[32];
    P.L_Wf2   = (const float*)d_in[33];
    P.L_bf2   = (const float*)d_in[34];
    P.p_lng   = (const float*)d_in[35];
    P.p_lnb   = (const float*)d_in[36];
    P.p_W1    = (const float*)d_in[37];
    P.p_b1    = (const float*)d_in[38];
    P.p_W2    = (const float*)d_in[39];
    P.p_b2    = (const float*)d_in[40];
    P.wsf     = (const uint4*)d_ws;
    P.out     = (float*)d_out;
    hipLaunchKernelGGL(prep_w, dim3(12), dim3(256), 0, stream,
                       P.Wv_emb, P.L_Wk, P.L_Wv, (uint4*)d_ws);
    hipLaunchKernelGGL(gora_fused, dim3(NB), dim3(256), 0, stream, P);
}